// Round 11
// baseline (55.803 us; speedup 1.0000x reference)
//
#include <hip/hip_runtime.h>
#include <hip/hip_bf16.h>
#include <stdint.h>
#include <math.h>

#define H_HT 26
#define W_HT 122
#define NPIX (H_HT * W_HT)   // 3172
#define NA 60
#define NR 125
#define NB 32
#define NC 4
#define NBC (NB * NC)        // 128
#define PH 288
#define PW 800
#define NSPLIT 16            // rho splits per angle; wave bins r = q*4+w + 64t
#define PIX_PT 13            // ceil(3172/256) pixels per thread in csr

#define GT_BLKS ((NPIX + 1) / 2)         // 1586 transpose-gather blocks
#define ZERO_BLKS 4

// ---- workspace layout (bytes) ----
#define WS_OFF   190336                    // int32 [60*126]          30240
#define WS_LIST  220608                    // uint16[60*3172]        380640
#define WS_PREDT 601280                    // float [3172*128]      1624064
#define WS_PVP   2225344                   // u64   [128*60]          61440

// ---------------- Kernel A: fused setup -------------------------------------
__global__ __launch_bounds__(256) void setup(const float* __restrict__ vote,
                                             const float* __restrict__ pred,
                                             int* __restrict__ off,
                                             uint16_t* __restrict__ list,
                                             float* __restrict__ pred_T,
                                             unsigned long long* __restrict__ pvp) {
    const int tid = threadIdx.x;
    if (blockIdx.x < NA) {
        const int a = blockIdx.x;
        __shared__ int s_cnt[NR];
        __shared__ int sc[2][NR];
        __shared__ int s_pre[NR + 1];
        __shared__ int s_cur[NR];

        float sn, cs;
        __sincosf((float)(a * 3) * 0.017453292519943295f, &sn, &cs);

        int  rloc[PIX_PT];
        bool grd[PIX_PT];
#pragma unroll
        for (int k = 0; k < PIX_PT; ++k) {
            int p = tid + k * 256;
            rloc[k] = 0; grd[k] = false;
            if (p < NPIX) {
                int h = p / W_HT;
                int w = p - h * W_HT;
                float xs = (float)w - 60.5f;
                float ys = (float)h - 12.5f;
                float rho = xs * cs + ys * sn;
                int r = (int)rintf(rho) + NR / 2;
                r = r < 0 ? 0 : (r > NR - 1 ? NR - 1 : r);
                rloc[k] = r;
                grd[k] = fabsf(rho - floorf(rho) - 0.5f) < 1e-3f;
            }
        }
        float vv[PIX_PT];
#pragma unroll
        for (int k = 0; k < PIX_PT; ++k) {
            int p = tid + k * 256;
            vv[k] = 1.0f;
            if (p < NPIX && grd[k])
                vv[k] = vote[(size_t)(p * NA + a) * NR + rloc[k]];
        }
#pragma unroll
        for (int k = 0; k < PIX_PT; ++k) {
            int p = tid + k * 256;
            if (p < NPIX && grd[k] && vv[k] == 0.0f) {
                const float* vrow = vote + (size_t)(p * NA + a) * NR;
                int r = rloc[k];
                if (r + 1 < NR && vrow[r + 1] != 0.0f) r = r + 1;
                else if (r - 1 >= 0 && vrow[r - 1] != 0.0f) r = r - 1;
                else {
                    for (int r2 = 0; r2 < NR; ++r2)
                        if (vrow[r2] != 0.0f) { r = r2; break; }
                }
                rloc[k] = r;
            }
        }
        for (int i = tid; i < NR; i += 256) s_cnt[i] = 0;
        __syncthreads();
#pragma unroll
        for (int k = 0; k < PIX_PT; ++k) {
            int p = tid + k * 256;
            if (p < NPIX) atomicAdd(&s_cnt[rloc[k]], 1);
        }
        __syncthreads();
        if (tid < NR) sc[0][tid] = s_cnt[tid];
        __syncthreads();
        int pin = 0;
        for (int d = 1; d < NR; d <<= 1) {
            if (tid < NR) {
                int v = sc[pin][tid];
                if (tid >= d) v += sc[pin][tid - d];
                sc[pin ^ 1][tid] = v;
            }
            __syncthreads();
            pin ^= 1;
        }
        if (tid == 0) s_pre[0] = 0;
        if (tid < NR) s_pre[tid + 1] = sc[pin][tid];
        __syncthreads();
        for (int r = tid; r < NR + 1; r += 256) off[a * (NR + 1) + r] = s_pre[r];
        for (int r = tid; r < NR; r += 256) s_cur[r] = s_pre[r];
        __syncthreads();
#pragma unroll
        for (int k = 0; k < PIX_PT; ++k) {
            int p = tid + k * 256;
            if (p < NPIX) {
                int slot = atomicAdd(&s_cur[rloc[k]], 1);
                list[a * NPIX + slot] = (uint16_t)p;
            }
        }
    } else if (blockIdx.x < NA + GT_BLKS) {
        const int bidx = blockIdx.x - NA;
        const int p  = bidx * 2 + (tid >> 7);
        const int bc = tid & 127;
        if (p < NPIX) {
            const float C1 = (float)(288.0 / 26.0);
            const float C2 = (float)(800.0 / 122.0);
            int h = p / W_HT;
            int w = p - h * W_HT;
            int hi = (int)floorf((float)h * C1);
            int wi = (int)floorf((float)w * C2);
            pred_T[p * NBC + bc] = pred[((size_t)bc * PH + hi) * PW + wi];
        }
    } else {
        int i0 = (blockIdx.x - NA - GT_BLKS) * 256 + tid;
        for (int i = i0; i < NA * NBC; i += ZERO_BLKS * 256) pvp[i] = 0ull;
    }
}

// ---------------- Kernel B: transposed hough, shfl-broadcast + 16-deep ILP --
// Block = (angle, q). Wave w owns bins r = q*4+w + 64t (<=2). For each bin:
// read its list segment coalesced (64 entries per 128B wave-load), broadcast
// each index via __shfl, keep 16 float2 loads in flight. No LDS, no barrier.
// Per-wave packed atomicMax merge (tie -> smaller bin).
__global__ __launch_bounds__(256) void hough_T5(const float* __restrict__ pred_T,
                                                const int* __restrict__ off,
                                                const uint16_t* __restrict__ list,
                                                unsigned long long* __restrict__ pvp) {
    const int blk  = blockIdx.x;
    const int a    = blk / NSPLIT;
    const int q    = blk - a * NSPLIT;
    const int tid  = threadIdx.x;
    const int w    = tid >> 6;
    const int lane = tid & 63;

    const float2* pT2 = reinterpret_cast<const float2*>(pred_T);
    const uint16_t* la = list + a * NPIX;
    const int* offa = off + a * (NR + 1);

    float bv0 = -1.0f, bv1 = -1.0f; int bi0 = 0x7fffffff, bi1 = 0x7fffffff;
    for (int r = q * 4 + w; r < NR; r += 64) {
        int o0 = offa[r];
        int o1 = offa[r + 1];
        float ax[4] = {0, 0, 0, 0}, ay[4] = {0, 0, 0, 0};
        for (int c0 = o0; c0 < o1; c0 += 64) {
            int nn = o1 - c0; if (nn > 64) nn = 64;
            int gidx = c0 + lane; if (gidx >= NPIX) gidx = NPIX - 1;
            int u = (int)la[gidx];                   // coalesced 128B
            for (int k0 = 0; k0 < nn; k0 += 16) {
                float2 v[16];
                int kn = nn - k0; if (kn > 16) kn = 16;
#pragma unroll
                for (int k = 0; k < 16; ++k) {
                    if (k < kn) {
                        int p = __shfl(u, k0 + k);   // wave-uniform pixel
                        v[k] = pT2[p * 64 + lane];   // 512B coalesced
                    }
                }
#pragma unroll
                for (int k = 0; k < 16; ++k) {
                    if (k < kn) { ax[k & 3] += v[k].x; ay[k & 3] += v[k].y; }
                }
            }
        }
        float sx = (ax[0] + ax[1]) + (ax[2] + ax[3]);
        float sy = (ay[0] + ay[1]) + (ay[2] + ay[3]);
        int gbin = a * NR + r;
        if (sx > bv0) { bv0 = sx; bi0 = gbin; }
        if (sy > bv1) { bv1 = sy; bi1 = gbin; }
    }
    unsigned long long e0 = ((unsigned long long)__float_as_uint(bv0 < 0.f ? 0.f : bv0) << 32)
                          | (unsigned long long)(65535 - bi0);
    unsigned long long e1 = ((unsigned long long)__float_as_uint(bv1 < 0.f ? 0.f : bv1) << 32)
                          | (unsigned long long)(65535 - bi1);
    atomicMax(&pvp[(2 * lane)     * NA + a], e0);
    atomicMax(&pvp[(2 * lane + 1) * NA + a], e1);
}

// ---------------- Kernel C: final argmax + gather + L1-normalize + loss -----
// 256 threads: wave = idx-channel k; lane = c*16 + s. Lane-parallel pvp
// argmax (packed u64 butterfly max); 16-way parallel L1 sum over angles.
__global__ __launch_bounds__(256) void loss4(const float* __restrict__ ht,
                                             const float* __restrict__ pexist,
                                             const unsigned long long* __restrict__ pvp,
                                             float* __restrict__ out) {
    __shared__ float s_sum[4];
    const int b    = blockIdx.x;
    const int tid  = threadIdx.x;
    const int k    = tid >> 6;      // wave = idx/exist channel
    const int lane = tid & 63;
    const int c    = lane >> 4;     // ht channel
    const int s    = lane & 15;

    // argmax over 60 angles for (b,k): one pvp entry per lane, butterfly max
    unsigned long long be = 0ull;
    if (lane < NA) be = pvp[(b * 4 + k) * NA + lane];
#pragma unroll
    for (int m = 32; m > 0; m >>= 1) {
        unsigned long long oe = __shfl_xor(be, m);
        if (oe > be) be = oe;
    }
    int fidx = 65535 - (int)(be & 0xFFFFull);
    int a0 = fidx / NR;
    int r  = fidx - a0 * NR;

    // L1 over 60 angles at rho=r for channel c: 16-way parallel, 4 loads each
    const float* htc = ht + (size_t)((b * 4 + c) * NA) * NR;
    float acc = 0.0f;
#pragma unroll
    for (int t = 0; t < 4; ++t) {
        int a = s + t * 16;
        if (a < NA) acc += fabsf(htc[a * NR + r]);
    }
#pragma unroll
    for (int m = 1; m < 16; m <<= 1) acc += __shfl_xor(acc, m);

    float term = 0.0f;
    if (s == 0) {
        float l1 = fmaxf(acc, 1e-12f);
        float gg = htc[a0 * NR + r] / l1;
        float ex = (pexist[b * 4 + k] > 0.9f) ? 1.0f : 0.0f;
        term = -logf(gg + 1e-12f) * ex;
    }
#pragma unroll
    for (int m = 16; m < 64; m <<= 1) term += __shfl_xor(term, m);
    if (lane == 0) s_sum[k] = term;
    __syncthreads();
    if (tid == 0)
        out[b] = (s_sum[0] + s_sum[1] + s_sum[2] + s_sum[3]) * (1.0f / 16.0f);
}

extern "C" void kernel_launch(void* const* d_in, const int* in_sizes, int n_in,
                              void* d_out, int out_size, void* d_ws, size_t ws_size,
                              hipStream_t stream) {
    const float* ht     = (const float*)d_in[0];
    const float* pred   = (const float*)d_in[1];
    const float* pexist = (const float*)d_in[2];
    const float* vote   = (const float*)d_in[3];

    char* ws = (char*)d_ws;
    int*      off    = (int*)     (ws + WS_OFF);
    uint16_t* list   = (uint16_t*)(ws + WS_LIST);
    float*    pred_T = (float*)   (ws + WS_PREDT);
    unsigned long long* pvp = (unsigned long long*)(ws + WS_PVP);

    setup<<<NA + GT_BLKS + ZERO_BLKS, 256, 0, stream>>>(vote, pred, off, list, pred_T, pvp);
    hough_T5<<<NA * NSPLIT, 256, 0, stream>>>(pred_T, off, list, pvp);
    loss4<<<NB, 256, 0, stream>>>(ht, pexist, pvp, (float*)d_out);
}